// Round 13
// baseline (733.607 us; speedup 1.0000x reference)
//
#include <hip/hip_runtime.h>
#include <math.h>

typedef unsigned short ushort_t;
typedef short short8 __attribute__((ext_vector_type(8)));
typedef short short4v __attribute__((ext_vector_type(4)));
typedef float f32x4  __attribute__((ext_vector_type(4)));

#define N_ROWS 8192
#define D_DIM  2048
#define K_CODES 10000
#define EPSF   1e-12f

#define BMT 128
#define BKT 64
#define KT_N 32          // D / BKT
#define MT 64            // 8192/128
#define NT 80            // 10240/128
#define NGROUP 320       // 32-col groups

#define BAND_ADD  2e-5f
#define FBIG 1e30f

__device__ __forceinline__ unsigned short f2bf(float f) {
  unsigned u = __float_as_uint(f);
  unsigned r = (u + 0x7fffu + ((u >> 16) & 1u)) >> 16;   // RNE
  return (unsigned short)r;
}
__device__ __forceinline__ float bf2f(unsigned short h) {
  return __uint_as_float(((unsigned)h) << 16);
}

__device__ __forceinline__ void stage16(const ushort_t* g, ushort_t* l) {
  __builtin_amdgcn_global_load_lds(
      (const __attribute__((address_space(1))) unsigned int*)g,
      (__attribute__((address_space(3))) unsigned int*)l, 16, 0, 0);
}

// ---- wave-per-row normalize (no barriers, no LDS): 4 rows per 256-block ----
// lane holds 32 elems; three sums reduced in one 6-step shuffle butterfly.
__global__ __launch_bounds__(256) void norm_hi_kernel(
    const float* __restrict__ src, ushort_t* __restrict__ hi,
    float* __restrict__ sq_out, float* __restrict__ inv_out,
    float* __restrict__ hn_out, float* __restrict__ ln_out, int nrows)
{
  const int wv   = threadIdx.x >> 6;
  const int lane = threadIdx.x & 63;
  const int row  = blockIdx.x * 4 + wv;
  if (row >= nrows) return;

  const float4* rp4 = (const float4*)(src + (size_t)row * D_DIM);
  float4 v[8];
  float s = 0.0f;
  #pragma unroll
  for (int j = 0; j < 8; ++j) {
    v[j] = rp4[lane + 64 * j];
    s += v[j].x*v[j].x + v[j].y*v[j].y + v[j].z*v[j].z + v[j].w*v[j].w;
  }
  #pragma unroll
  for (int off = 32; off > 0; off >>= 1) s += __shfl_xor(s, off, 64);
  const float inv = 1.0f / fmaxf(sqrtf(s), EPSF);

  float t = 0.0f, th = 0.0f, tl = 0.0f;
  #pragma unroll
  for (int j = 0; j < 8; ++j) {
    float e[4] = {v[j].x, v[j].y, v[j].z, v[j].w};
    unsigned short hb[4];
    #pragma unroll
    for (int i = 0; i < 4; ++i) {
      float xn = e[i] * inv;
      t += xn * xn;
      unsigned short h = f2bf(xn);
      hb[i] = h;
      float hf = bf2f(h);
      th += hf * hf;
      float l = xn - hf;     // exact (Sterbenz)
      tl += l * l;
    }
    *(short4v*)(hi + (size_t)row * D_DIM + (lane + 64 * j) * 4) = *(short4v*)hb;
  }
  #pragma unroll
  for (int off = 32; off > 0; off >>= 1) {
    t  += __shfl_xor(t,  off, 64);
    th += __shfl_xor(th, off, 64);
    tl += __shfl_xor(tl, off, 64);
  }
  if (lane == 0) {
    sq_out[row]  = t;
    hn_out[row]  = sqrtf(th);
    ln_out[row]  = sqrtf(tl);
    inv_out[row] = inv;
  }
}

// global maxima of ||wh||, ||wl|| over all codes (1 block, LDS tree reduce)
__global__ __launch_bounds__(256) void wmax_kernel(
    const float* __restrict__ whn, const float* __restrict__ wln,
    float* __restrict__ wmax_out)
{
  int tid = threadIdx.x;
  float mh = 0.0f, ml = 0.0f;
  for (int k = tid; k < K_CODES; k += 256) {
    mh = fmaxf(mh, whn[k]);
    ml = fmaxf(ml, wln[k]);
  }
  __shared__ float sh[256], sl[256];
  sh[tid] = mh; sl[tid] = ml;
  __syncthreads();
  #pragma unroll
  for (int o = 128; o > 0; o >>= 1) {
    if (tid < o) {
      sh[tid] = fmaxf(sh[tid], sh[tid + o]);
      sl[tid] = fmaxf(sl[tid], sl[tid + o]);
    }
    __syncthreads();
  }
  if (tid == 0) { wmax_out[0] = sh[0]; wmax_out[1] = sl[0]; }
}

// lexicographic less on (d, idx)
#define LEXLT(da, ia, db, ib) ((da) < (db) || ((da) == (db) && (ia) < (ib)))

// ---- 128x128 hi-only MFMA dist (round-9 proven: BK=64, 32 KB LDS, 419 us) ----
#define STAGE_A(KKO) { \
  _Pragma("unroll") for (int j = 0; j < 4; ++j) \
    stage16(Ah + (size_t)(row0 + w4*32 + j*8 + sub) * D_DIM + (KKO) + lsl, \
            lA + w4*2048 + j*512); }

#define STAGE_B(KKO) { \
  _Pragma("unroll") for (int j = 0; j < 4; ++j) { \
    int rr = col0 + w4*32 + j*8 + sub; rr = rr < K_CODES ? rr : K_CODES - 1; \
    stage16(Bh + (size_t)rr * D_DIM + (KKO) + lsl, \
            lB + w4*2048 + j*512); } }

#define COMPUTE_HALF(AP, BP) { \
  _Pragma("unroll") for (int m = 0; m < 4; ++m) \
    af[m] = *(const short8*)((AP) + m*1024); \
  _Pragma("unroll") for (int n = 0; n < 4; ++n) \
    bf[n] = *(const short8*)((BP) + n*1024); \
  _Pragma("unroll") for (int m = 0; m < 4; ++m) \
  _Pragma("unroll") for (int n = 0; n < 4; ++n) \
    acc[m][n] = __builtin_amdgcn_mfma_f32_16x16x32_bf16( \
        af[m], bf[n], acc[m][n], 0, 0, 0); }

__global__ __launch_bounds__(256, 4) void dist_top2_kernel(
    const ushort_t* __restrict__ Ah, const ushort_t* __restrict__ Bh,
    const float* __restrict__ wsq,
    float* __restrict__ p1d, int* __restrict__ p1i, float* __restrict__ p2d)
{
  __shared__ ushort_t lA[8192];   // [128 rows][64 k] bf16, swizzled slots
  __shared__ ushort_t lB[8192];

  const int tid  = threadIdx.x;
  const int lane = tid & 63;
  const int w4   = tid >> 6;        // wave 0..3
  const int wm   = w4 >> 1;         // wave row 0..1
  const int wn   = w4 & 1;          // wave col 0..1
  const int t16  = lane & 15;
  const int h4   = lane >> 4;

  // col-major block order: consecutive bids share ntile -> B-panel L2 reuse
  const int mtile = blockIdx.x & 63;
  const int ntile = blockIdx.x >> 6;
  const int row0 = mtile * BMT;
  const int col0 = ntile * BMT;

  // staging: wave w stages rows w*32 + j*8 + sub (j=0..3) for A and B
  const int sub = lane >> 3;                 // 0..7
  const int lsl = ((lane & 7) ^ sub) * 8;    // pre-swizzled source slot

  // fragment read bases: row rA = wX*64 + m*16 + t16, slot = (kc*4+h4)^(rA&7);
  // rA&7 == t16&7 -> slot constant across m.
  const ushort_t* aP0 = &lA[(wm*64 + t16)*64 + ((h4       ^ (t16 & 7)) * 8)];
  const ushort_t* aP1 = &lA[(wm*64 + t16)*64 + (((4 + h4) ^ (t16 & 7)) * 8)];
  const ushort_t* bP0 = &lB[(wn*64 + t16)*64 + ((h4       ^ (t16 & 7)) * 8)];
  const ushort_t* bP1 = &lB[(wn*64 + t16)*64 + (((4 + h4) ^ (t16 & 7)) * 8)];

  f32x4 acc[4][4];
  #pragma unroll
  for (int m = 0; m < 4; ++m)
    #pragma unroll
    for (int n = 0; n < 4; ++n) acc[m][n] = (f32x4){0.f, 0.f, 0.f, 0.f};

  short8 af[4], bf[4];

  for (int kt = 0; kt < KT_N; ++kt) {
    const int kk = kt * BKT;
    STAGE_A(kk);
    STAGE_B(kk);
    __syncthreads();            // compiler drains vmcnt before barrier: data ready
    COMPUTE_HALF(aP0, bP0);     // kc = 0
    COMPUTE_HALF(aP1, bP1);     // kc = 1
    __syncthreads();            // all reads done before next stage overwrites
  }

  // ---- epilogue: per (row, 32-col group) top-1 (d,i) + 2nd-best d ----
  float wsqr[4]; int colr[4];
  #pragma unroll
  for (int n = 0; n < 4; ++n) {
    int col = col0 + wn * 64 + n * 16 + t16;
    colr[n] = col;
    wsqr[n] = (col < K_CODES) ? wsq[col] : FBIG * 10.0f;
  }
  #pragma unroll
  for (int m = 0; m < 4; ++m) {
    int rloc = wm * 64 + m * 16 + h4 * 4;
    #pragma unroll
    for (int j = 0; j < 4; ++j) {
      #pragma unroll
      for (int half = 0; half < 2; ++half) {
        int na = half * 2, nb = na + 1;
        float da = wsqr[na] - 2.0f * acc[m][na][j]; int ia = colr[na];
        float db = wsqr[nb] - 2.0f * acc[m][nb][j]; int ib = colr[nb];
        float d1, d2; int i1;
        if (LEXLT(db, ib, da, ia)) { d1 = db; i1 = ib; d2 = da; }
        else                       { d1 = da; i1 = ia; d2 = db; }
        #pragma unroll
        for (int off = 1; off < 16; off <<= 1) {
          float od1 = __shfl_xor(d1, off, 64);
          int   oi1 = __shfl_xor(i1, off, 64);
          float od2 = __shfl_xor(d2, off, 64);
          if (LEXLT(od1, oi1, d1, i1)) { d2 = fminf(d1, od2); d1 = od1; i1 = oi1; }
          else                         { d2 = fminf(od1, d2); }
        }
        if (t16 == 0) {
          int grow = row0 + rloc + j;
          int gid = ntile * 4 + wn * 2 + half;
          size_t o = (size_t)grow * NGROUP + gid;
          p1d[o] = d1; p1i[o] = i1; p2d[o] = d2;
        }
      }
    }
  }
}

// per-row band screen + exact fp32 refinement + fused gather & loss partial.
// One wave per row.
__global__ __launch_bounds__(256) void refine_gather_kernel(
    const float* __restrict__ x, const float* __restrict__ w,
    const float* __restrict__ xsq, const float* __restrict__ xinv,
    const float* __restrict__ xhn, const float* __restrict__ xln,
    const float* __restrict__ wsq, const float* __restrict__ winv,
    const float* __restrict__ whn, const float* __restrict__ wln,
    const float* __restrict__ wmax,
    const float* __restrict__ p1d, const int* __restrict__ p1i,
    const float* __restrict__ p2d,
    float* __restrict__ out, float* __restrict__ lpart,
    float* __restrict__ idxf_out)
{
  const int wv   = threadIdx.x >> 6;
  const int lane = threadIdx.x & 63;
  const int row  = blockIdx.x * 4 + wv;

  const float xs = xsq[row], xh = xhn[row], xl = xln[row];
  const float whm = wmax[0], wlm = wmax[1];
  const float eps_max = 2.0f * (xl * whm + xh * wlm + xl * wlm) + BAND_ADD;

  // group stats: lane owns groups lane + 64*s
  float gd1[5], gd2[5], geps[5];
  int   gi1[5];
  float tmin = FBIG;
  float bmind = FBIG; int bmink = 0x7fffffff;
  #pragma unroll
  for (int s = 0; s < 5; ++s) {
    size_t o = (size_t)row * NGROUP + lane + 64 * s;
    float d1 = p1d[o]; int i1 = p1i[o]; float d2 = p2d[o];
    int is = i1 < K_CODES ? i1 : K_CODES - 1;
    float e1 = 2.0f * (xl * whn[is] + xh * wln[is] + xl * wln[is]) + BAND_ADD;
    gd1[s] = d1; gi1[s] = i1; gd2[s] = d2; geps[s] = e1;
    tmin = fminf(tmin, d1 + e1);
    if (d1 < bmind || (d1 == bmind && i1 < bmink)) { bmind = d1; bmink = i1; }
  }
  #pragma unroll
  for (int off = 1; off < 64; off <<= 1) tmin = fminf(tmin, __shfl_xor(tmin, off, 64));
  const float T = tmin;

  // global screen-min code across lanes
  #pragma unroll
  for (int off = 1; off < 64; off <<= 1) {
    float od = __shfl_xor(bmind, off, 64);
    int   ok = __shfl_xor(bmink, off, 64);
    if (od < bmind || (od == bmind && ok < bmink)) { bmind = od; bmink = ok; }
  }
  const int kfirst = bmink;

  unsigned long long ms[5], mc[5];
  int ncand = 0, nscan = 0;
  #pragma unroll
  for (int s = 0; s < 5; ++s) {
    bool scan = (gd2[s] - eps_max <= T);
    bool cand = !scan && (gd1[s] - geps[s] <= T);
    ms[s] = __ballot(scan); mc[s] = __ballot(cand);
    nscan += __popcll(ms[s]); ncand += __popcll(mc[s]);
  }

  int bi = kfirst;
  if (!(nscan == 0 && ncand == 1)) {
    // ---- slow path: exact fp32 distances ----
    const float4* xr4 = (const float4*)(x + (size_t)row * D_DIM);
    const float xiv = xinv[row];
    float4 xv[8];
    #pragma unroll
    for (int j = 0; j < 8; ++j) {
      float4 v = xr4[lane + 64 * j];
      v.x *= xiv; v.y *= xiv; v.z *= xiv; v.w *= xiv;
      xv[j] = v;
    }

    float bd = INFINITY; bi = 0x7fffffff;
    auto refine = [&](int k) {
      const float4* wr4 = (const float4*)(w + (size_t)k * D_DIM);
      const float wiv = winv[k];
      float a = 0.0f;
      #pragma unroll
      for (int j = 0; j < 8; ++j) {
        float4 wvv = wr4[lane + 64 * j];
        a += xv[j].x * (wvv.x * wiv) + xv[j].y * (wvv.y * wiv)
           + xv[j].z * (wvv.z * wiv) + xv[j].w * (wvv.w * wiv);
      }
      #pragma unroll
      for (int off = 32; off > 0; off >>= 1) a += __shfl_xor(a, off, 64);
      float df = (xs + wsq[k]) - 2.0f * a;
      if (df < bd || (df == bd && k < bi)) { bd = df; bi = k; }
    };

    if (kfirst < K_CODES) refine(kfirst);

    #pragma unroll
    for (int s = 0; s < 5; ++s) {
      unsigned long long m = mc[s];
      while (m) {
        int lsrc = __ffsll(m) - 1; m &= m - 1;
        int k = __shfl(gi1[s], lsrc, 64);
        if (k == kfirst || k >= K_CODES) continue;
        float a1d = __shfl(gd1[s],  lsrc, 64);
        float a1e = __shfl(geps[s], lsrc, 64);
        if (a1d - a1e <= bd + BAND_ADD) refine(k);
      }
      m = ms[s];
      while (m) {
        int lsrc = __ffsll(m) - 1; m &= m - 1;
        float a2d = __shfl(gd2[s], lsrc, 64);
        if (a2d - eps_max > bd + BAND_ADD) continue;
        int k0 = (lsrc + 64 * s) * 32;
        for (int kk = 0; kk < 32; ++kk) {
          int k = k0 + kk;
          if (k < K_CODES) refine(k);
        }
      }
    }
  }

  // ---- fused gather + loss partial: out[row] = w[bi]; lpart = sum((w-x)^2) ----
  {
    const float4* wr4 = (const float4*)(w + (size_t)bi * D_DIM);
    const float4* xr4 = (const float4*)(x + (size_t)row * D_DIM);
    float4* og = (float4*)(out + (size_t)row * D_DIM);
    float s = 0.0f;
    #pragma unroll
    for (int j = 0; j < 8; ++j) {
      float4 wvv = wr4[lane + 64 * j];
      float4 xvv = xr4[lane + 64 * j];
      og[lane + 64 * j] = wvv;
      float d0 = wvv.x - xvv.x, d1 = wvv.y - xvv.y;
      float d2 = wvv.z - xvv.z, d3 = wvv.w - xvv.w;
      s += d0 * d0 + d1 * d1 + d2 * d2 + d3 * d3;
    }
    #pragma unroll
    for (int off = 32; off > 0; off >>= 1) s += __shfl_xor(s, off, 64);
    if (lane == 0) { lpart[row] = s; idxf_out[row] = (float)bi; }
  }
}

__global__ __launch_bounds__(256) void loss_kernel(const float* __restrict__ lpart,
                                                   float* __restrict__ loss_out)
{
  int tid = threadIdx.x;
  double s = 0.0;
  for (int t = tid; t < N_ROWS; t += 256) s += (double)lpart[t];
  __shared__ double sd[256];
  sd[tid] = s;
  __syncthreads();
  #pragma unroll
  for (int o = 128; o > 0; o >>= 1) {
    if (tid < o) sd[tid] += sd[tid + o];
    __syncthreads();
  }
  if (tid == 0)
    loss_out[0] = (float)(1.25 * sd[0] / (double)((size_t)N_ROWS * (size_t)D_DIM));
}

extern "C" void kernel_launch(void* const* d_in, const int* in_sizes, int n_in,
                              void* d_out, int out_size, void* d_ws, size_t ws_size,
                              hipStream_t stream) {
  const float* x = (const float*)d_in[0];
  const float* w = (const float*)d_in[1];
  float* out = (float*)d_out;
  char*  ws  = (char*)d_ws;

  size_t off = 0;
  auto alloc = [&](size_t bytes) {
    size_t o = off;
    off = (off + bytes + 255) & ~(size_t)255;
    return o;
  };
  const size_t szA1 = (size_t)N_ROWS * D_DIM * 2;
  const size_t szB1 = (size_t)K_CODES * D_DIM * 2;
  const size_t szP  = (size_t)NGROUP * N_ROWS * 4;

  ushort_t* Bh = (ushort_t*)(ws + alloc(szB1));
  float* wsq  = (float*)(ws + alloc((size_t)K_CODES * 4));
  float* winv = (float*)(ws + alloc((size_t)K_CODES * 4));
  float* whn  = (float*)(ws + alloc((size_t)K_CODES * 4));
  float* wln  = (float*)(ws + alloc((size_t)K_CODES * 4));
  float* wmax = (float*)(ws + alloc(2 * 4));
  float* xsq  = (float*)(ws + alloc((size_t)N_ROWS * 4));
  float* xinv = (float*)(ws + alloc((size_t)N_ROWS * 4));
  float* xhn  = (float*)(ws + alloc((size_t)N_ROWS * 4));
  float* xln  = (float*)(ws + alloc((size_t)N_ROWS * 4));
  float* p1d  = (float*)(ws + alloc(szP));
  int*   p1i  = (int*)  (ws + alloc(szP));
  float* p2d  = (float*)(ws + alloc(szP));
  float* lpart = (float*)(ws + alloc((size_t)N_ROWS * 4));

  ushort_t* Ahp;
  if (ws_size >= off + szA1) {
    Ahp = (ushort_t*)(ws + alloc(szA1));
  } else {
    // quantized region (N*D*4 bytes) as scratch; consumed by dist kernel,
    // then overwritten by refine_gather_kernel (stream-ordered, safe)
    Ahp = (ushort_t*)out;
  }

  float* loss_out = out + (size_t)N_ROWS * D_DIM;
  float* idxf_out = loss_out + 1;

  norm_hi_kernel<<<N_ROWS / 4, 256, 0, stream>>>(
      x, Ahp, xsq, xinv, xhn, xln, N_ROWS);
  norm_hi_kernel<<<K_CODES / 4, 256, 0, stream>>>(
      w, Bh, wsq, winv, whn, wln, K_CODES);
  wmax_kernel<<<1, 256, 0, stream>>>(whn, wln, wmax);
  dist_top2_kernel<<<MT * NT, 256, 0, stream>>>(
      Ahp, Bh, wsq, p1d, p1i, p2d);
  refine_gather_kernel<<<N_ROWS / 4, 256, 0, stream>>>(
      x, w, xsq, xinv, xhn, xln, wsq, winv, whn, wln, wmax,
      p1d, p1i, p2d, out, lpart, idxf_out);
  loss_kernel<<<1, 256, 0, stream>>>(lpart, loss_out);
}

// Round 14
// 727.669 us; speedup vs baseline: 1.0082x; 1.0082x over previous
//
#include <hip/hip_runtime.h>
#include <math.h>

typedef unsigned short ushort_t;
typedef short short8 __attribute__((ext_vector_type(8)));
typedef short short4v __attribute__((ext_vector_type(4)));
typedef float f32x4  __attribute__((ext_vector_type(4)));

#define N_ROWS 8192
#define D_DIM  2048
#define K_CODES 10000
#define EPSF   1e-12f

#define BMT 128
#define BKT 64
#define KT_N 32          // D / BKT
#define MT 64            // 8192/128
#define NT 80            // 10240/128
#define NGROUP 320       // 32-col groups

#define BAND_ADD  2e-5f
#define FBIG 1e30f

__device__ __forceinline__ unsigned short f2bf(float f) {
  unsigned u = __float_as_uint(f);
  unsigned r = (u + 0x7fffu + ((u >> 16) & 1u)) >> 16;   // RNE
  return (unsigned short)r;
}
__device__ __forceinline__ float bf2f(unsigned short h) {
  return __uint_as_float(((unsigned)h) << 16);
}

__device__ __forceinline__ void stage16(const ushort_t* g, ushort_t* l) {
  __builtin_amdgcn_global_load_lds(
      (const __attribute__((address_space(1))) unsigned int*)g,
      (__attribute__((address_space(3))) unsigned int*)l, 16, 0, 0);
}

// ---- fused wave-per-row normalize for BOTH x and w (no atomics) ----
// global wave-row r: r < N_ROWS -> x row r ; else w row r - N_ROWS.
__global__ __launch_bounds__(256) void norm_all_kernel(
    const float* __restrict__ x, const float* __restrict__ w,
    ushort_t* __restrict__ xhi, ushort_t* __restrict__ whi,
    float* __restrict__ xsq, float* __restrict__ xinv,
    float* __restrict__ xhn, float* __restrict__ xln,
    float* __restrict__ wsq, float* __restrict__ winv,
    float* __restrict__ whn, float* __restrict__ wln)
{
  const int wv   = threadIdx.x >> 6;
  const int lane = threadIdx.x & 63;
  const int r    = blockIdx.x * 4 + wv;
  const bool isx = r < N_ROWS;
  const int row  = isx ? r : r - N_ROWS;
  if (!isx && row >= K_CODES) return;
  const float* src = isx ? x : w;
  ushort_t* hi = isx ? xhi : whi;

  const float4* rp4 = (const float4*)(src + (size_t)row * D_DIM);
  float4 v[8];
  float s = 0.0f;
  #pragma unroll
  for (int j = 0; j < 8; ++j) {
    v[j] = rp4[lane + 64 * j];
    s += v[j].x*v[j].x + v[j].y*v[j].y + v[j].z*v[j].z + v[j].w*v[j].w;
  }
  #pragma unroll
  for (int off = 32; off > 0; off >>= 1) s += __shfl_xor(s, off, 64);
  const float inv = 1.0f / fmaxf(sqrtf(s), EPSF);

  float t = 0.0f, th = 0.0f, tl = 0.0f;
  #pragma unroll
  for (int j = 0; j < 8; ++j) {
    float e[4] = {v[j].x, v[j].y, v[j].z, v[j].w};
    unsigned short hb[4];
    #pragma unroll
    for (int i = 0; i < 4; ++i) {
      float xn = e[i] * inv;
      t += xn * xn;
      unsigned short h = f2bf(xn);
      hb[i] = h;
      float hf = bf2f(h);
      th += hf * hf;
      float l = xn - hf;     // exact (Sterbenz)
      tl += l * l;
    }
    *(short4v*)(hi + (size_t)row * D_DIM + (lane + 64 * j) * 4) = *(short4v*)hb;
  }
  #pragma unroll
  for (int off = 32; off > 0; off >>= 1) {
    t  += __shfl_xor(t,  off, 64);
    th += __shfl_xor(th, off, 64);
    tl += __shfl_xor(tl, off, 64);
  }
  if (lane == 0) {
    if (isx) {
      xsq[row] = t; xhn[row] = sqrtf(th); xln[row] = sqrtf(tl); xinv[row] = inv;
    } else {
      wsq[row] = t; whn[row] = sqrtf(th); wln[row] = sqrtf(tl); winv[row] = inv;
    }
  }
}

// global maxima of ||wh||, ||wl|| over all codes (1 block, LDS tree reduce)
__global__ __launch_bounds__(256) void wmax_kernel(
    const float* __restrict__ whn, const float* __restrict__ wln,
    float* __restrict__ wmax_out)
{
  int tid = threadIdx.x;
  float mh = 0.0f, ml = 0.0f;
  for (int k = tid; k < K_CODES; k += 256) {
    mh = fmaxf(mh, whn[k]);
    ml = fmaxf(ml, wln[k]);
  }
  __shared__ float sh[256], sl[256];
  sh[tid] = mh; sl[tid] = ml;
  __syncthreads();
  #pragma unroll
  for (int o = 128; o > 0; o >>= 1) {
    if (tid < o) {
      sh[tid] = fmaxf(sh[tid], sh[tid + o]);
      sl[tid] = fmaxf(sl[tid], sl[tid + o]);
    }
    __syncthreads();
  }
  if (tid == 0) { wmax_out[0] = sh[0]; wmax_out[1] = sl[0]; }
}

// lexicographic less on (d, idx)
#define LEXLT(da, ia, db, ib) ((da) < (db) || ((da) == (db) && (ia) < (ib)))

// ---- 128x128 hi-only MFMA dist; XCD-private 16m x 40n regions ----
// Co-resident blocks per XCD then share only ~26 panel K-slices (416 KB)
// per K-step -> staging served from L2 instead of thrashing to L3.
#define STAGE_A(KKO) { \
  _Pragma("unroll") for (int j = 0; j < 4; ++j) \
    stage16(Ah + (size_t)(row0 + w4*32 + j*8 + sub) * D_DIM + (KKO) + lsl, \
            lA + w4*2048 + j*512); }

#define STAGE_B(KKO) { \
  _Pragma("unroll") for (int j = 0; j < 4; ++j) { \
    int rr = col0 + w4*32 + j*8 + sub; rr = rr < K_CODES ? rr : K_CODES - 1; \
    stage16(Bh + (size_t)rr * D_DIM + (KKO) + lsl, \
            lB + w4*2048 + j*512); } }

#define COMPUTE_HALF(AP, BP) { \
  _Pragma("unroll") for (int m = 0; m < 4; ++m) \
    af[m] = *(const short8*)((AP) + m*1024); \
  _Pragma("unroll") for (int n = 0; n < 4; ++n) \
    bf[n] = *(const short8*)((BP) + n*1024); \
  _Pragma("unroll") for (int m = 0; m < 4; ++m) \
  _Pragma("unroll") for (int n = 0; n < 4; ++n) \
    acc[m][n] = __builtin_amdgcn_mfma_f32_16x16x32_bf16( \
        af[m], bf[n], acc[m][n], 0, 0, 0); }

__global__ __launch_bounds__(256, 4) void dist_top2_kernel(
    const ushort_t* __restrict__ Ah, const ushort_t* __restrict__ Bh,
    const float* __restrict__ wsq,
    float* __restrict__ p1d, int* __restrict__ p1i, float* __restrict__ p2d)
{
  __shared__ ushort_t lA[8192];   // [128 rows][64 k] bf16, swizzled slots
  __shared__ ushort_t lB[8192];

  const int tid  = threadIdx.x;
  const int lane = tid & 63;
  const int w4   = tid >> 6;        // wave 0..3
  const int wm   = w4 >> 1;         // wave row 0..1
  const int wn   = w4 & 1;          // wave col 0..1
  const int t16  = lane & 15;
  const int h4   = lane >> 4;

  // XCD-chunked mapping: bid&7 -> XCD (round-robin dispatch); each XCD owns a
  // contiguous 16m x 40n region, walked col-major (m fast).
  const int xcd = blockIdx.x & 7;
  const int l   = blockIdx.x >> 3;        // 0..639
  const int lm  = l & 15;
  const int ln  = l >> 4;                 // 0..39
  const int mtile = (xcd & 3) * 16 + lm;
  const int ntile = (xcd >> 2) * 40 + ln;
  const int row0 = mtile * BMT;
  const int col0 = ntile * BMT;

  // staging: wave w stages rows w*32 + j*8 + sub (j=0..3) for A and B
  const int sub = lane >> 3;                 // 0..7
  const int lsl = ((lane & 7) ^ sub) * 8;    // pre-swizzled source slot

  // fragment read bases: row rA = wX*64 + m*16 + t16, slot = (kc*4+h4)^(rA&7);
  // rA&7 == t16&7 -> slot constant across m.
  const ushort_t* aP0 = &lA[(wm*64 + t16)*64 + ((h4       ^ (t16 & 7)) * 8)];
  const ushort_t* aP1 = &lA[(wm*64 + t16)*64 + (((4 + h4) ^ (t16 & 7)) * 8)];
  const ushort_t* bP0 = &lB[(wn*64 + t16)*64 + ((h4       ^ (t16 & 7)) * 8)];
  const ushort_t* bP1 = &lB[(wn*64 + t16)*64 + (((4 + h4) ^ (t16 & 7)) * 8)];

  f32x4 acc[4][4];
  #pragma unroll
  for (int m = 0; m < 4; ++m)
    #pragma unroll
    for (int n = 0; n < 4; ++n) acc[m][n] = (f32x4){0.f, 0.f, 0.f, 0.f};

  short8 af[4], bf[4];

  for (int kt = 0; kt < KT_N; ++kt) {
    const int kk = kt * BKT;
    STAGE_A(kk);
    STAGE_B(kk);
    __syncthreads();            // compiler drains vmcnt before barrier: data ready
    COMPUTE_HALF(aP0, bP0);     // kc = 0
    COMPUTE_HALF(aP1, bP1);     // kc = 1
    __syncthreads();            // all reads done before next stage overwrites
  }

  // ---- epilogue: per (row, 32-col group) top-1 (d,i) + 2nd-best d ----
  float wsqr[4]; int colr[4];
  #pragma unroll
  for (int n = 0; n < 4; ++n) {
    int col = col0 + wn * 64 + n * 16 + t16;
    colr[n] = col;
    wsqr[n] = (col < K_CODES) ? wsq[col] : FBIG * 10.0f;
  }
  #pragma unroll
  for (int m = 0; m < 4; ++m) {
    int rloc = wm * 64 + m * 16 + h4 * 4;
    #pragma unroll
    for (int j = 0; j < 4; ++j) {
      #pragma unroll
      for (int half = 0; half < 2; ++half) {
        int na = half * 2, nb = na + 1;
        float da = wsqr[na] - 2.0f * acc[m][na][j]; int ia = colr[na];
        float db = wsqr[nb] - 2.0f * acc[m][nb][j]; int ib = colr[nb];
        float d1, d2; int i1;
        if (LEXLT(db, ib, da, ia)) { d1 = db; i1 = ib; d2 = da; }
        else                       { d1 = da; i1 = ia; d2 = db; }
        #pragma unroll
        for (int off = 1; off < 16; off <<= 1) {
          float od1 = __shfl_xor(d1, off, 64);
          int   oi1 = __shfl_xor(i1, off, 64);
          float od2 = __shfl_xor(d2, off, 64);
          if (LEXLT(od1, oi1, d1, i1)) { d2 = fminf(d1, od2); d1 = od1; i1 = oi1; }
          else                         { d2 = fminf(od1, d2); }
        }
        if (t16 == 0) {
          int grow = row0 + rloc + j;
          int gid = ntile * 4 + wn * 2 + half;
          size_t o = (size_t)grow * NGROUP + gid;
          p1d[o] = d1; p1i[o] = i1; p2d[o] = d2;
        }
      }
    }
  }
}

// per-row band screen + exact fp32 refinement + fused gather & loss partial.
// One wave per row.
__global__ __launch_bounds__(256) void refine_gather_kernel(
    const float* __restrict__ x, const float* __restrict__ w,
    const float* __restrict__ xsq, const float* __restrict__ xinv,
    const float* __restrict__ xhn, const float* __restrict__ xln,
    const float* __restrict__ wsq, const float* __restrict__ winv,
    const float* __restrict__ whn, const float* __restrict__ wln,
    const float* __restrict__ wmax,
    const float* __restrict__ p1d, const int* __restrict__ p1i,
    const float* __restrict__ p2d,
    float* __restrict__ out, float* __restrict__ lpart,
    float* __restrict__ idxf_out)
{
  const int wv   = threadIdx.x >> 6;
  const int lane = threadIdx.x & 63;
  const int row  = blockIdx.x * 4 + wv;

  const float xs = xsq[row], xh = xhn[row], xl = xln[row];
  const float whm = wmax[0], wlm = wmax[1];
  const float eps_max = 2.0f * (xl * whm + xh * wlm + xl * wlm) + BAND_ADD;

  // group stats: lane owns groups lane + 64*s
  float gd1[5], gd2[5], geps[5];
  int   gi1[5];
  float tmin = FBIG;
  float bmind = FBIG; int bmink = 0x7fffffff;
  #pragma unroll
  for (int s = 0; s < 5; ++s) {
    size_t o = (size_t)row * NGROUP + lane + 64 * s;
    float d1 = p1d[o]; int i1 = p1i[o]; float d2 = p2d[o];
    int is = i1 < K_CODES ? i1 : K_CODES - 1;
    float e1 = 2.0f * (xl * whn[is] + xh * wln[is] + xl * wln[is]) + BAND_ADD;
    gd1[s] = d1; gi1[s] = i1; gd2[s] = d2; geps[s] = e1;
    tmin = fminf(tmin, d1 + e1);
    if (d1 < bmind || (d1 == bmind && i1 < bmink)) { bmind = d1; bmink = i1; }
  }
  #pragma unroll
  for (int off = 1; off < 64; off <<= 1) tmin = fminf(tmin, __shfl_xor(tmin, off, 64));
  const float T = tmin;

  // global screen-min code across lanes
  #pragma unroll
  for (int off = 1; off < 64; off <<= 1) {
    float od = __shfl_xor(bmind, off, 64);
    int   ok = __shfl_xor(bmink, off, 64);
    if (od < bmind || (od == bmind && ok < bmink)) { bmind = od; bmink = ok; }
  }
  const int kfirst = bmink;

  unsigned long long ms[5], mc[5];
  int ncand = 0, nscan = 0;
  #pragma unroll
  for (int s = 0; s < 5; ++s) {
    bool scan = (gd2[s] - eps_max <= T);
    bool cand = !scan && (gd1[s] - geps[s] <= T);
    ms[s] = __ballot(scan); mc[s] = __ballot(cand);
    nscan += __popcll(ms[s]); ncand += __popcll(mc[s]);
  }

  int bi = kfirst;
  if (!(nscan == 0 && ncand == 1)) {
    // ---- slow path: exact fp32 distances ----
    const float4* xr4 = (const float4*)(x + (size_t)row * D_DIM);
    const float xiv = xinv[row];
    float4 xv[8];
    #pragma unroll
    for (int j = 0; j < 8; ++j) {
      float4 v = xr4[lane + 64 * j];
      v.x *= xiv; v.y *= xiv; v.z *= xiv; v.w *= xiv;
      xv[j] = v;
    }

    float bd = INFINITY; bi = 0x7fffffff;
    auto refine = [&](int k) {
      const float4* wr4 = (const float4*)(w + (size_t)k * D_DIM);
      const float wiv = winv[k];
      float a = 0.0f;
      #pragma unroll
      for (int j = 0; j < 8; ++j) {
        float4 wvv = wr4[lane + 64 * j];
        a += xv[j].x * (wvv.x * wiv) + xv[j].y * (wvv.y * wiv)
           + xv[j].z * (wvv.z * wiv) + xv[j].w * (wvv.w * wiv);
      }
      #pragma unroll
      for (int off = 32; off > 0; off >>= 1) a += __shfl_xor(a, off, 64);
      float df = (xs + wsq[k]) - 2.0f * a;
      if (df < bd || (df == bd && k < bi)) { bd = df; bi = k; }
    };

    if (kfirst < K_CODES) refine(kfirst);

    #pragma unroll
    for (int s = 0; s < 5; ++s) {
      unsigned long long m = mc[s];
      while (m) {
        int lsrc = __ffsll(m) - 1; m &= m - 1;
        int k = __shfl(gi1[s], lsrc, 64);
        if (k == kfirst || k >= K_CODES) continue;
        float a1d = __shfl(gd1[s],  lsrc, 64);
        float a1e = __shfl(geps[s], lsrc, 64);
        if (a1d - a1e <= bd + BAND_ADD) refine(k);
      }
      m = ms[s];
      while (m) {
        int lsrc = __ffsll(m) - 1; m &= m - 1;
        float a2d = __shfl(gd2[s], lsrc, 64);
        if (a2d - eps_max > bd + BAND_ADD) continue;
        int k0 = (lsrc + 64 * s) * 32;
        for (int kk = 0; kk < 32; ++kk) {
          int k = k0 + kk;
          if (k < K_CODES) refine(k);
        }
      }
    }
  }

  // ---- fused gather + loss partial: out[row] = w[bi]; lpart = sum((w-x)^2) ----
  {
    const float4* wr4 = (const float4*)(w + (size_t)bi * D_DIM);
    const float4* xr4 = (const float4*)(x + (size_t)row * D_DIM);
    float4* og = (float4*)(out + (size_t)row * D_DIM);
    float s = 0.0f;
    #pragma unroll
    for (int j = 0; j < 8; ++j) {
      float4 wvv = wr4[lane + 64 * j];
      float4 xvv = xr4[lane + 64 * j];
      og[lane + 64 * j] = wvv;
      float d0 = wvv.x - xvv.x, d1 = wvv.y - xvv.y;
      float d2 = wvv.z - xvv.z, d3 = wvv.w - xvv.w;
      s += d0 * d0 + d1 * d1 + d2 * d2 + d3 * d3;
    }
    #pragma unroll
    for (int off = 32; off > 0; off >>= 1) s += __shfl_xor(s, off, 64);
    if (lane == 0) { lpart[row] = s; idxf_out[row] = (float)bi; }
  }
}

__global__ __launch_bounds__(256) void loss_kernel(const float* __restrict__ lpart,
                                                   float* __restrict__ loss_out)
{
  int tid = threadIdx.x;
  double s = 0.0;
  for (int t = tid; t < N_ROWS; t += 256) s += (double)lpart[t];
  __shared__ double sd[256];
  sd[tid] = s;
  __syncthreads();
  #pragma unroll
  for (int o = 128; o > 0; o >>= 1) {
    if (tid < o) sd[tid] += sd[tid + o];
    __syncthreads();
  }
  if (tid == 0)
    loss_out[0] = (float)(1.25 * sd[0] / (double)((size_t)N_ROWS * (size_t)D_DIM));
}

extern "C" void kernel_launch(void* const* d_in, const int* in_sizes, int n_in,
                              void* d_out, int out_size, void* d_ws, size_t ws_size,
                              hipStream_t stream) {
  const float* x = (const float*)d_in[0];
  const float* w = (const float*)d_in[1];
  float* out = (float*)d_out;
  char*  ws  = (char*)d_ws;

  size_t off = 0;
  auto alloc = [&](size_t bytes) {
    size_t o = off;
    off = (off + bytes + 255) & ~(size_t)255;
    return o;
  };
  const size_t szA1 = (size_t)N_ROWS * D_DIM * 2;
  const size_t szB1 = (size_t)K_CODES * D_DIM * 2;
  const size_t szP  = (size_t)NGROUP * N_ROWS * 4;

  ushort_t* Bh = (ushort_t*)(ws + alloc(szB1));
  float* wsq  = (float*)(ws + alloc((size_t)K_CODES * 4));
  float* winv = (float*)(ws + alloc((size_t)K_CODES * 4));
  float* whn  = (float*)(ws + alloc((size_t)K_CODES * 4));
  float* wln  = (float*)(ws + alloc((size_t)K_CODES * 4));
  float* wmax = (float*)(ws + alloc(2 * 4));
  float* xsq  = (float*)(ws + alloc((size_t)N_ROWS * 4));
  float* xinv = (float*)(ws + alloc((size_t)N_ROWS * 4));
  float* xhn  = (float*)(ws + alloc((size_t)N_ROWS * 4));
  float* xln  = (float*)(ws + alloc((size_t)N_ROWS * 4));
  float* p1d  = (float*)(ws + alloc(szP));
  int*   p1i  = (int*)  (ws + alloc(szP));
  float* p2d  = (float*)(ws + alloc(szP));
  float* lpart = (float*)(ws + alloc((size_t)N_ROWS * 4));

  ushort_t* Ahp;
  if (ws_size >= off + szA1) {
    Ahp = (ushort_t*)(ws + alloc(szA1));
  } else {
    // quantized region (N*D*4 bytes) as scratch; consumed by dist kernel,
    // then overwritten by refine_gather_kernel (stream-ordered, safe)
    Ahp = (ushort_t*)out;
  }

  float* loss_out = out + (size_t)N_ROWS * D_DIM;
  float* idxf_out = loss_out + 1;

  norm_all_kernel<<<(N_ROWS + K_CODES + 3) / 4, 256, 0, stream>>>(
      x, w, Ahp, Bh, xsq, xinv, xhn, xln, wsq, winv, whn, wln);
  wmax_kernel<<<1, 256, 0, stream>>>(whn, wln, wmax);
  dist_top2_kernel<<<MT * NT, 256, 0, stream>>>(
      Ahp, Bh, wsq, p1d, p1i, p2d);
  refine_gather_kernel<<<N_ROWS / 4, 256, 0, stream>>>(
      x, w, xsq, xinv, xhn, xln, wsq, winv, whn, wln, wmax,
      p1d, p1i, p2d, out, lpart, idxf_out);
  loss_kernel<<<1, 256, 0, stream>>>(lpart, loss_out);
}